// Round 1
// baseline (1664.512 us; speedup 1.0000x reference)
//
#include <hip/hip_runtime.h>
#include <hip/hip_bf16.h>

#define BF16 __hip_bfloat16

typedef __bf16 bf16x8 __attribute__((ext_vector_type(8)));
typedef float f32x4 __attribute__((ext_vector_type(4)));

__device__ __forceinline__ void async_copy16(const void* g, void* l) {
    __builtin_amdgcn_global_load_lds(
        (const __attribute__((address_space(1))) void*)g,
        (__attribute__((address_space(3))) void*)l,
        16, 0, 0);
}

// ---------------- fp32 -> bf16 convert with K padding ----------------
__global__ __launch_bounds__(256) void convert_pad_k(
    const float* __restrict__ src, BF16* __restrict__ dst,
    long pairs, int Ks, int Kd) {
    long p = (long)blockIdx.x * blockDim.x + threadIdx.x;
    if (p >= pairs) return;
    long e = p * 2;
    long r = e / Kd;
    int k = (int)(e - r * Kd);
    float a = (k < Ks) ? src[r * Ks + k] : 0.f;
    float b = (k + 1 < Ks) ? src[r * Ks + k + 1] : 0.f;
    dst[e] = __float2bfloat16(a);
    dst[e + 1] = __float2bfloat16(b);
}

// ---------------- NT GEMM: out[n][m] = act(sum_k X[n][k]*W[m][k] + bias[m]) ---
// X: [N][K] bf16, W: [512][K] bf16, out: [N][512] bf16. N mult of 128, K mult of 32.
__global__ __launch_bounds__(256) void gemm_nt(
    const BF16* __restrict__ Xg, const BF16* __restrict__ Wg,
    const float* __restrict__ bias, BF16* __restrict__ Og,
    int K, int act) {
    __shared__ __align__(16) BF16 Xs[128 * 32];
    __shared__ __align__(16) BF16 Ws[128 * 32];
    const int tid = threadIdx.x;
    const int w = tid >> 6;
    const int lane = tid & 63;
    const int quad = lane >> 4;
    const int l15 = lane & 15;
    const long n0 = (long)blockIdx.x * 128;
    const int m0 = blockIdx.y * 128;
    const int wn = (w & 1) * 64;
    const int wm = (w >> 1) * 64;
    const int srow = lane >> 2;        // 0..15
    const int skoff = (lane & 3) * 8;  // element offset within 32-wide K tile
    f32x4 acc[4][4] = {};
    for (int k0 = 0; k0 < K; k0 += 32) {
#pragma unroll
        for (int c = 0; c < 2; ++c) {
            const int rbase = w * 32 + c * 16;
            async_copy16(Xg + (n0 + rbase + srow) * K + k0 + skoff, &Xs[rbase * 32]);
            async_copy16(Wg + (long)(m0 + rbase + srow) * K + k0 + skoff, &Ws[rbase * 32]);
        }
        __syncthreads();
        bf16x8 af[4], bfr[4];
#pragma unroll
        for (int i = 0; i < 4; ++i)
            af[i] = *(const bf16x8*)&Xs[(wn + i * 16 + l15) * 32 + quad * 8];
#pragma unroll
        for (int j = 0; j < 4; ++j)
            bfr[j] = *(const bf16x8*)&Ws[(wm + j * 16 + l15) * 32 + quad * 8];
#pragma unroll
        for (int i = 0; i < 4; ++i)
#pragma unroll
            for (int j = 0; j < 4; ++j)
                acc[i][j] = __builtin_amdgcn_mfma_f32_16x16x32_bf16(af[i], bfr[j], acc[i][j], 0, 0, 0);
        __syncthreads();
    }
#pragma unroll
    for (int j = 0; j < 4; ++j) {
        const int m = m0 + wm + j * 16 + l15;
        const float bz = bias[m];
#pragma unroll
        for (int i = 0; i < 4; ++i) {
#pragma unroll
            for (int r = 0; r < 4; ++r) {
                const long n = n0 + wn + i * 16 + quad * 4 + r;
                float v = acc[i][j][r] + bz;
                if (act) v = (v >= 0.f) ? v : 0.01f * v;
                Og[n * 512 + m] = __float2bfloat16(v);
            }
        }
    }
}

// ---------------- attention scores + softmax, one block per batch ----------------
// Q,K: [33280][512] bf16 (rows bb*65 .. bb*65+64). Sg: [512][65][96] bf16, cols>=65 zero.
__global__ __launch_bounds__(256) void attn_scores_k(
    const BF16* __restrict__ Qg, const BF16* __restrict__ Kg, BF16* __restrict__ Sg) {
    constexpr float SC = 0.04419417382415922f;  // 1/sqrt(512)
    __shared__ __align__(16) BF16 Qs[80 * 40];
    __shared__ __align__(16) BF16 Ks[80 * 40];
    __shared__ float Sf[80 * 84];
    const int bb = blockIdx.x;
    const int tid = threadIdx.x;
    const int w = tid >> 6, lane = tid & 63, quad = lane >> 4, l15 = lane & 15;
    f32x4 acc[2][5] = {};
    for (int k0 = 0; k0 < 512; k0 += 32) {
        for (int idx = tid; idx < 640; idx += 256) {
            const int t = (idx >= 320) ? 1 : 0;
            const int e = idx - t * 320;
            const int row = e >> 2;
            const int koff = (e & 3) * 8;
            uint4 val = make_uint4(0, 0, 0, 0);
            if (row < 65) {
                const BF16* src = (t ? Kg : Qg) + ((long)(bb * 65 + row) * 512 + k0 + koff);
                val = *(const uint4*)src;
            }
            *(uint4*)&((t ? Ks : Qs)[row * 40 + koff]) = val;
        }
        __syncthreads();
#pragma unroll
        for (int rep = 0; rep < 2; ++rep) {
            const int i = w + rep * 4;
            if (i < 5) {
                bf16x8 af = *(const bf16x8*)&Qs[(i * 16 + l15) * 40 + quad * 8];
#pragma unroll
                for (int j = 0; j < 5; ++j) {
                    bf16x8 bfr = *(const bf16x8*)&Ks[(j * 16 + l15) * 40 + quad * 8];
                    acc[rep][j] = __builtin_amdgcn_mfma_f32_16x16x32_bf16(af, bfr, acc[rep][j], 0, 0, 0);
                }
            }
        }
        __syncthreads();
    }
#pragma unroll
    for (int rep = 0; rep < 2; ++rep) {
        const int i = w + rep * 4;
        if (i < 5) {
#pragma unroll
            for (int j = 0; j < 5; ++j)
#pragma unroll
                for (int r = 0; r < 4; ++r)
                    Sf[(i * 16 + quad * 4 + r) * 84 + j * 16 + l15] = acc[rep][j][r] * SC;
        }
    }
    __syncthreads();
    if (tid < 65) {
        const int row = tid;
        float mx = -1e30f;
        for (int m = 0; m < 65; ++m) mx = fmaxf(mx, Sf[row * 84 + m]);
        float s = 0.f;
        for (int m = 0; m < 65; ++m) s += __expf(Sf[row * 84 + m] - mx);
        const float inv = 1.f / s;
        const long base = ((long)bb * 65 + row) * 96;
        for (int m = 0; m < 96; ++m) {
            float v = (m < 65) ? __expf(Sf[row * 84 + m] - mx) * inv : 0.f;
            Sg[base + m] = __float2bfloat16(v);
        }
    }
}

// ---------------- PV + residual, one block per batch ----------------
// X[bb*65+l][c] = sum_m S[bb][l][m] * V[bb*65+m][c] (+ X if residual)
__global__ __launch_bounds__(256) void attn_pv_k(
    const BF16* __restrict__ Sg, const BF16* __restrict__ Vg,
    BF16* __restrict__ Xg, int residual) {
    __shared__ __align__(16) BF16 Ss[80 * 104];
    __shared__ __align__(16) BF16 Vt[512 * 104];
    const int bb = blockIdx.x;
    const int tid = threadIdx.x;
    const int w = tid >> 6, lane = tid & 63, quad = lane >> 4, l15 = lane & 15;
    for (int e = tid; e < 80 * 96; e += 256) {
        const int row = e / 96, m = e - row * 96;
        BF16 v = __float2bfloat16(0.f);
        if (row < 65) v = Sg[((long)bb * 65 + row) * 96 + m];
        Ss[row * 104 + m] = v;
    }
    for (int e = tid; e < 65 * 512; e += 256) {
        const int m = e >> 9, c = e & 511;
        Vt[c * 104 + m] = Vg[((long)bb * 65 + m) * 512 + c];
    }
    for (int e = tid; e < 512 * 31; e += 256) {
        const int c = e / 31, m = 65 + (e - c * 31);
        Vt[c * 104 + m] = __float2bfloat16(0.f);
    }
    __syncthreads();
    const int c0 = w * 128;
#pragma unroll
    for (int i = 0; i < 5; ++i) {
        f32x4 acc[8] = {};
#pragma unroll
        for (int ks = 0; ks < 3; ++ks) {
            bf16x8 af = *(const bf16x8*)&Ss[(i * 16 + l15) * 104 + ks * 32 + quad * 8];
#pragma unroll
            for (int j = 0; j < 8; ++j) {
                bf16x8 bfr = *(const bf16x8*)&Vt[(c0 + j * 16 + l15) * 104 + ks * 32 + quad * 8];
                acc[j] = __builtin_amdgcn_mfma_f32_16x16x32_bf16(af, bfr, acc[j], 0, 0, 0);
            }
        }
#pragma unroll
        for (int j = 0; j < 8; ++j) {
#pragma unroll
            for (int r = 0; r < 4; ++r) {
                const int l = i * 16 + quad * 4 + r;
                if (l < 65) {
                    const long idx = ((long)bb * 65 + l) * 512 + c0 + j * 16 + l15;
                    float v = acc[j][r];
                    if (residual) v += __bfloat162float(Xg[idx]);
                    Xg[idx] = __float2bfloat16(v);
                }
            }
        }
    }
}

// ---------------- mean over L -> Hp[b][s*512+c] fp32 ----------------
__global__ __launch_bounds__(256) void pool_k(const BF16* __restrict__ Xg,
                                              float* __restrict__ Hp) {
    const int sb = blockIdx.x;  // s*256+b
    const int s = sb >> 8, b = sb & 255;
    for (int c = threadIdx.x; c < 512; c += 256) {
        float acc = 0.f;
        for (int l = 0; l < 65; ++l)
            acc += __bfloat162float(Xg[((long)sb * 65 + l) * 512 + c]);
        Hp[(long)b * 1024 + s * 512 + c] = acc * (1.f / 65.f);
    }
}

// ---------------- classifier: relu(Hp@W1^T+b1) @ W2^T + b2 -> out[256][2] ----
__global__ __launch_bounds__(256) void fc_k(
    const float* __restrict__ Hp, const float* __restrict__ W1,
    const float* __restrict__ b1, const float* __restrict__ W2,
    const float* __restrict__ b2, float* __restrict__ out) {
    __shared__ float h[1024];
    __shared__ float h1[256];
    const int b = blockIdx.x, tid = threadIdx.x;
    for (int k = tid; k < 1024; k += 256) h[k] = Hp[(long)b * 1024 + k];
    __syncthreads();
    float acc = b1[tid];
    for (int k = 0; k < 1024; ++k) acc += W1[(long)tid * 1024 + k] * h[k];
    h1[tid] = fmaxf(acc, 0.f);
    __syncthreads();
    const int w = tid >> 6, lane = tid & 63;
    if (w < 2) {
        float p = 0.f;
        for (int u = lane; u < 256; u += 64) p += W2[w * 256 + u] * h1[u];
        for (int off = 32; off > 0; off >>= 1) p += __shfl_down(p, off);
        if (lane == 0) out[b * 2 + w] = p + b2[w];
    }
}

extern "C" void kernel_launch(void* const* d_in, const int* in_sizes, int n_in,
                              void* d_out, int out_size, void* d_ws, size_t ws_size,
                              hipStream_t stream) {
    const float* dataL = (const float*)d_in[0];
    const float* dataR = (const float*)d_in[1];
    const float* Wq0 = (const float*)d_in[2];
    const float* bq0 = (const float*)d_in[3];
    const float* Wk0 = (const float*)d_in[4];
    const float* bk0 = (const float*)d_in[5];
    const float* Wv0 = (const float*)d_in[6];
    const float* bv0 = (const float*)d_in[7];
    const float* Wq = (const float*)d_in[8];
    const float* bq = (const float*)d_in[9];
    const float* Wk = (const float*)d_in[10];
    const float* bk = (const float*)d_in[11];
    const float* Wv = (const float*)d_in[12];
    const float* bv = (const float*)d_in[13];
    const float* W1 = (const float*)d_in[14];
    const float* b1 = (const float*)d_in[15];
    const float* W2 = (const float*)d_in[16];
    const float* b2 = (const float*)d_in[17];

    // ws layout (bytes):
    //   Xb   @ 0          : 33280 x 2080 bf16 = 138,444,800   (X aliases first 34 MB after layer 0)
    //   Wc   @ 138444800  : bf16 weights, 11,108,352
    //   Q    @ 149553152  : 33280 x 512 bf16 = 34,078,720
    //   K    @ 183631872
    //   V    @ 217710592
    //   S    @ 251789312  : 512 x 65 x 96 bf16 = 6,389,760
    //   Hp   @ 258179072  : 256 x 1024 f32 = 1,048,576      -> total 259,227,648
    char* ws = (char*)d_ws;
    BF16* Xb = (BF16*)ws;
    BF16* Wc = (BF16*)(ws + 138444800L);
    BF16* Qb = (BF16*)(ws + 149553152L);
    BF16* Kb = (BF16*)(ws + 183631872L);
    BF16* Vb = (BF16*)(ws + 217710592L);
    BF16* Sb = (BF16*)(ws + 251789312L);
    float* Hp = (float*)(ws + 258179072L);
    BF16* X = Xb;  // alias: Xb dead after layer-0 QKV

    BF16* wq0 = Wc;
    BF16* wk0 = Wc + 512L * 2080;
    BF16* wv0 = Wc + 2L * 512 * 2080;
    BF16* wq1 = Wc + 3L * 512 * 2080;
    BF16* wk1 = wq1 + 3L * 262144;
    BF16* wv1 = wq1 + 6L * 262144;

    auto cvt = [&](const float* src, BF16* dst, long R, int Ks, int Kd) {
        long pairs = R * Kd / 2;
        int blocks = (int)((pairs + 255) / 256);
        convert_pad_k<<<blocks, 256, 0, stream>>>(src, dst, pairs, Ks, Kd);
    };
    cvt(dataL, Xb, 16640, 2053, 2080);
    cvt(dataR, Xb + 16640L * 2080, 16640, 2053, 2080);
    cvt(Wq0, wq0, 512, 2053, 2080);
    cvt(Wk0, wk0, 512, 2053, 2080);
    cvt(Wv0, wv0, 512, 2053, 2080);
    cvt(Wq, wq1, 1536, 512, 512);
    cvt(Wk, wk1, 1536, 512, 512);
    cvt(Wv, wv1, 1536, 512, 512);

    dim3 ggrid(260, 4);
    // layer 0 (CIN=2053 padded to 2080; no residual)
    gemm_nt<<<ggrid, 256, 0, stream>>>(Xb, wq0, bq0, Qb, 2080, 0);
    gemm_nt<<<ggrid, 256, 0, stream>>>(Xb, wk0, bk0, Kb, 2080, 0);
    gemm_nt<<<ggrid, 256, 0, stream>>>(Xb, wv0, bv0, Vb, 2080, 1);
    attn_scores_k<<<512, 256, 0, stream>>>(Qb, Kb, Sb);
    attn_pv_k<<<512, 256, 0, stream>>>(Sb, Vb, X, 0);
    // layers 1..3 (C->C, residual)
    for (int n = 0; n < 3; ++n) {
        gemm_nt<<<ggrid, 256, 0, stream>>>(X, wq1 + (long)n * 262144, bq + n * 512, Qb, 512, 0);
        gemm_nt<<<ggrid, 256, 0, stream>>>(X, wk1 + (long)n * 262144, bk + n * 512, Kb, 512, 0);
        gemm_nt<<<ggrid, 256, 0, stream>>>(X, wv1 + (long)n * 262144, bv + n * 512, Vb, 512, 1);
        attn_scores_k<<<512, 256, 0, stream>>>(Qb, Kb, Sb);
        attn_pv_k<<<512, 256, 0, stream>>>(Sb, Vb, X, 1);
    }
    pool_k<<<512, 256, 0, stream>>>(X, Hp);
    fc_k<<<256, 256, 0, stream>>>(Hp, W1, b1, W2, b2, (float*)d_out);
}

// Round 2
// 1600.173 us; speedup vs baseline: 1.0402x; 1.0402x over previous
//
#include <hip/hip_runtime.h>
#include <hip/hip_bf16.h>

#define BF16 __hip_bfloat16

typedef __bf16 bf16x8 __attribute__((ext_vector_type(8)));
typedef float f32x4 __attribute__((ext_vector_type(4)));

__device__ __forceinline__ void async_copy16(const void* g, void* l) {
    __builtin_amdgcn_global_load_lds(
        (const __attribute__((address_space(1))) void*)g,
        (__attribute__((address_space(3))) void*)l,
        16, 0, 0);
}

// ---------------- fp32 -> bf16 convert with K padding ----------------
__global__ __launch_bounds__(256) void convert_pad_k(
    const float* __restrict__ src, BF16* __restrict__ dst,
    long pairs, int Ks, int Kd) {
    long p = (long)blockIdx.x * blockDim.x + threadIdx.x;
    if (p >= pairs) return;
    long e = p * 2;
    long r = e / Kd;
    int k = (int)(e - r * Kd);
    float a = (k < Ks) ? src[r * Ks + k] : 0.f;
    float b = (k + 1 < Ks) ? src[r * Ks + k + 1] : 0.f;
    dst[e] = __float2bfloat16(a);
    dst[e + 1] = __float2bfloat16(b);
}

// ---------------- fused QKV NT GEMM ----------------
// X: [N][K] bf16, W packed: [1536][K] = Wq|Wk|Wv. grid (12, 260): x = m-tile, y = n-tile.
// sel = x>>2 routes output: Q rows, K rows, V (vtmode: transposed [bb][c][96], else rows).
__global__ __launch_bounds__(256) void gemm_qkv(
    const BF16* __restrict__ Xg, const BF16* __restrict__ Wg,
    const float* __restrict__ bqp, const float* __restrict__ bkp, const float* __restrict__ bvp,
    BF16* __restrict__ Qo, BF16* __restrict__ Ko, BF16* __restrict__ Vo,
    int K, int vtmode) {
    __shared__ __align__(16) BF16 Xs[128 * 32];
    __shared__ __align__(16) BF16 Ws[128 * 32];
    const int tid = threadIdx.x;
    const int w = tid >> 6;
    const int lane = tid & 63;
    const int quad = lane >> 4;
    const int l15 = lane & 15;
    const long n0 = (long)blockIdx.y * 128;
    const int m0full = blockIdx.x * 128;
    const int sel = blockIdx.x >> 2;
    const int mbase = (blockIdx.x & 3) * 128;
    const int wn = (w & 1) * 64;
    const int wm = (w >> 1) * 64;
    const int srow = lane >> 2;
    const int skoff = (lane & 3) * 8;
    f32x4 acc[4][4] = {};
    for (int k0 = 0; k0 < K; k0 += 32) {
#pragma unroll
        for (int c = 0; c < 2; ++c) {
            const int rbase = w * 32 + c * 16;
            async_copy16(Xg + (n0 + rbase + srow) * K + k0 + skoff, &Xs[rbase * 32]);
            async_copy16(Wg + (long)(m0full + rbase + srow) * K + k0 + skoff, &Ws[rbase * 32]);
        }
        __syncthreads();
        bf16x8 af[4], bfr[4];
#pragma unroll
        for (int i = 0; i < 4; ++i)
            af[i] = *(const bf16x8*)&Xs[(wn + i * 16 + l15) * 32 + quad * 8];
#pragma unroll
        for (int j = 0; j < 4; ++j)
            bfr[j] = *(const bf16x8*)&Ws[(wm + j * 16 + l15) * 32 + quad * 8];
#pragma unroll
        for (int i = 0; i < 4; ++i)
#pragma unroll
            for (int j = 0; j < 4; ++j)
                acc[i][j] = __builtin_amdgcn_mfma_f32_16x16x32_bf16(af[i], bfr[j], acc[i][j], 0, 0, 0);
        __syncthreads();
    }
    const float* bp = (sel == 0) ? bqp : (sel == 1) ? bkp : bvp;
    BF16* out = (sel == 0) ? Qo : (sel == 1) ? Ko : Vo;
#pragma unroll
    for (int j = 0; j < 4; ++j) {
        const int m = mbase + wm + j * 16 + l15;
        const float bz = bp[m];
#pragma unroll
        for (int i = 0; i < 4; ++i) {
#pragma unroll
            for (int r = 0; r < 4; ++r) {
                const long n = n0 + wn + i * 16 + quad * 4 + r;
                float v = acc[i][j][r] + bz;
                if (sel == 2) {
                    v = (v >= 0.f) ? v : 0.01f * v;
                    if (vtmode) {
                        const int bb = (int)(n / 65);
                        const int l = (int)(n - (long)bb * 65);
                        out[((long)bb * 512 + m) * 96 + l] = __float2bfloat16(v);
                        continue;
                    }
                }
                out[n * 512 + m] = __float2bfloat16(v);
            }
        }
    }
}

// ---------------- V transpose (layer 0 only): Vb[n][512] -> Vt[bb][c][96] ----------------
__global__ __launch_bounds__(256) void vtrans_k(const ushort* __restrict__ Vb,
                                                ushort* __restrict__ Vt) {
    const int bb = blockIdx.x;
    for (int idx = threadIdx.x; idx < 512 * 33; idx += 256) {
        const int c = idx / 33;
        const int m = (idx - c * 33) * 2;
        ushort a = Vb[((long)bb * 65 + m) * 512 + c];
        ushort b = (m + 1 < 65) ? Vb[((long)bb * 65 + m + 1) * 512 + c] : (ushort)0;
        *(uint*)&Vt[((long)bb * 512 + c) * 96 + m] = (uint)a | ((uint)b << 16);
    }
}

// ---------------- fused attention: scores + softmax + PV (+residual), one block/batch ---
// Q,K: [33280][512] bf16; Vt: [bb][c][96] bf16 (m>=65 pad ignored); X: [33280][512] in/out.
__global__ __launch_bounds__(256) void attn_fused(
    const BF16* __restrict__ Qg, const BF16* __restrict__ Kg,
    const BF16* __restrict__ Vt, BF16* __restrict__ Xg, int residual) {
    constexpr float SC = 0.04419417382415922f;  // 1/sqrt(512)
    __shared__ __align__(16) BF16 Qs[80 * 40];
    __shared__ __align__(16) BF16 Ks[80 * 40];
    __shared__ float Sf[80 * 84];
    __shared__ __align__(16) BF16 Ps[80 * 104];
    __shared__ float inv[80];
    const int bb = blockIdx.x;
    const int tid = threadIdx.x;
    const int w = tid >> 6, lane = tid & 63, quad = lane >> 4, l15 = lane & 15;
    // ---- phase 1: S = Q K^T * SC ----
    f32x4 acc[2][5] = {};
    for (int k0 = 0; k0 < 512; k0 += 32) {
        for (int idx = tid; idx < 640; idx += 256) {
            const int t = (idx >= 320) ? 1 : 0;
            const int e = idx - t * 320;
            const int row = e >> 2;
            const int koff = (e & 3) * 8;
            uint4 val = make_uint4(0, 0, 0, 0);
            if (row < 65) {
                const BF16* src = (t ? Kg : Qg) + ((long)(bb * 65 + row) * 512 + k0 + koff);
                val = *(const uint4*)src;
            }
            *(uint4*)&((t ? Ks : Qs)[row * 40 + koff]) = val;
        }
        __syncthreads();
#pragma unroll
        for (int rep = 0; rep < 2; ++rep) {
            const int i = w + rep * 4;
            if (i < 5) {
                bf16x8 af = *(const bf16x8*)&Qs[(i * 16 + l15) * 40 + quad * 8];
#pragma unroll
                for (int j = 0; j < 5; ++j) {
                    bf16x8 bfr = *(const bf16x8*)&Ks[(j * 16 + l15) * 40 + quad * 8];
                    acc[rep][j] = __builtin_amdgcn_mfma_f32_16x16x32_bf16(af, bfr, acc[rep][j], 0, 0, 0);
                }
            }
        }
        __syncthreads();
    }
#pragma unroll
    for (int rep = 0; rep < 2; ++rep) {
        const int i = w + rep * 4;
        if (i < 5) {
#pragma unroll
            for (int j = 0; j < 5; ++j)
#pragma unroll
                for (int r = 0; r < 4; ++r)
                    Sf[(i * 16 + quad * 4 + r) * 84 + j * 16 + l15] = acc[rep][j][r] * SC;
        }
    }
    // zero P (pad cols/rows must be 0 for the PV MFMAs)
    for (int e = tid; e < 80 * 104 / 2; e += 256) ((uint*)Ps)[e] = 0u;
    __syncthreads();
    // ---- phase 2: softmax rows (4 threads per row), unnormalized P + inv ----
    for (int rr = tid >> 2; rr < 65; rr += 64) {
        const int sub = tid & 3;
        float mx = -1e30f;
        for (int m = sub; m < 65; m += 4) mx = fmaxf(mx, Sf[rr * 84 + m]);
        mx = fmaxf(mx, __shfl_xor(mx, 1));
        mx = fmaxf(mx, __shfl_xor(mx, 2));
        float s = 0.f;
        for (int m = sub; m < 65; m += 4) {
            float p = __expf(Sf[rr * 84 + m] - mx);
            s += p;
            Ps[rr * 104 + m] = __float2bfloat16(p);
        }
        s += __shfl_xor(s, 1);
        s += __shfl_xor(s, 2);
        if (sub == 0) inv[rr] = 1.f / s;
    }
    __syncthreads();
    // ---- phase 3: O = (P V) * inv (+X). B-frags straight from global Vt. ----
    bf16x8 af[5][3];
#pragma unroll
    for (int i = 0; i < 5; ++i)
#pragma unroll
        for (int ks = 0; ks < 3; ++ks)
            af[i][ks] = *(const bf16x8*)&Ps[(i * 16 + l15) * 104 + ks * 32 + quad * 8];
    float invv[5][4];
#pragma unroll
    for (int i = 0; i < 5; ++i)
#pragma unroll
        for (int r = 0; r < 4; ++r) {
            const int l = i * 16 + quad * 4 + r;
            invv[i][r] = (l < 65) ? inv[l] : 0.f;
        }
    for (int jj = 0; jj < 8; ++jj) {
        const int jt = w + jj * 4;
        const int c = jt * 16 + l15;
        const BF16* vp = Vt + ((long)bb * 512 + c) * 96 + quad * 8;
        bf16x8 b0 = *(const bf16x8*)vp;
        bf16x8 b1 = *(const bf16x8*)(vp + 32);
        bf16x8 b2 = *(const bf16x8*)(vp + 64);
        f32x4 po[5] = {};
#pragma unroll
        for (int i = 0; i < 5; ++i) {
            po[i] = __builtin_amdgcn_mfma_f32_16x16x32_bf16(af[i][0], b0, po[i], 0, 0, 0);
            po[i] = __builtin_amdgcn_mfma_f32_16x16x32_bf16(af[i][1], b1, po[i], 0, 0, 0);
            po[i] = __builtin_amdgcn_mfma_f32_16x16x32_bf16(af[i][2], b2, po[i], 0, 0, 0);
        }
#pragma unroll
        for (int i = 0; i < 5; ++i)
#pragma unroll
            for (int r = 0; r < 4; ++r) {
                const int l = i * 16 + quad * 4 + r;
                if (l < 65) {
                    const long idx = ((long)(bb * 65 + l)) * 512 + c;
                    float v = po[i][r] * invv[i][r];
                    if (residual) v += __bfloat162float(Xg[idx]);
                    Xg[idx] = __float2bfloat16(v);
                }
            }
    }
}

// ---------------- mean over L -> Hp[b][s*512+c] fp32 ----------------
__global__ __launch_bounds__(256) void pool_k(const BF16* __restrict__ Xg,
                                              float* __restrict__ Hp) {
    const int sb = blockIdx.x;
    const int s = sb >> 8, b = sb & 255;
    for (int c = threadIdx.x; c < 512; c += 256) {
        float acc = 0.f;
        for (int l = 0; l < 65; ++l)
            acc += __bfloat162float(Xg[((long)sb * 65 + l) * 512 + c]);
        Hp[(long)b * 1024 + s * 512 + c] = acc * (1.f / 65.f);
    }
}

// ---------------- classifier ----------------
__global__ __launch_bounds__(256) void fc_k(
    const float* __restrict__ Hp, const float* __restrict__ W1,
    const float* __restrict__ b1, const float* __restrict__ W2,
    const float* __restrict__ b2, float* __restrict__ out) {
    __shared__ float h[1024];
    __shared__ float h1[256];
    const int b = blockIdx.x, tid = threadIdx.x;
    for (int k = tid; k < 1024; k += 256) h[k] = Hp[(long)b * 1024 + k];
    __syncthreads();
    float acc = b1[tid];
    for (int k = 0; k < 1024; ++k) acc += W1[(long)tid * 1024 + k] * h[k];
    h1[tid] = fmaxf(acc, 0.f);
    __syncthreads();
    const int w = tid >> 6, lane = tid & 63;
    if (w < 2) {
        float p = 0.f;
        for (int u = lane; u < 256; u += 64) p += W2[w * 256 + u] * h1[u];
        for (int off = 32; off > 0; off >>= 1) p += __shfl_down(p, off);
        if (lane == 0) out[b * 2 + w] = p + b2[w];
    }
}

extern "C" void kernel_launch(void* const* d_in, const int* in_sizes, int n_in,
                              void* d_out, int out_size, void* d_ws, size_t ws_size,
                              hipStream_t stream) {
    const float* dataL = (const float*)d_in[0];
    const float* dataR = (const float*)d_in[1];
    const float* Wq0 = (const float*)d_in[2];
    const float* bq0 = (const float*)d_in[3];
    const float* Wk0 = (const float*)d_in[4];
    const float* bk0 = (const float*)d_in[5];
    const float* Wv0 = (const float*)d_in[6];
    const float* bv0 = (const float*)d_in[7];
    const float* Wq = (const float*)d_in[8];
    const float* bq = (const float*)d_in[9];
    const float* Wk = (const float*)d_in[10];
    const float* bk = (const float*)d_in[11];
    const float* Wv = (const float*)d_in[12];
    const float* bv = (const float*)d_in[13];
    const float* W1 = (const float*)d_in[14];
    const float* b1 = (const float*)d_in[15];
    const float* W2 = (const float*)d_in[16];
    const float* b2 = (const float*)d_in[17];

    // ws layout (bytes), total 252,837,888 (<= round-1's proven 259 MB):
    //   Xb  @ 0          : 33280 x 2080 bf16 = 138,444,800 (layer-0 input; dead after L0 GEMM)
    //     X  @ 0         : 33280 x 512 bf16 = 34,078,720 (aliases Xb head)
    //     Vt @ 34078720  : 512 x 512 x 96 bf16 = 50,331,648 (aliases Xb tail)
    //   Wc  @ 138444800  : packed bf16 weights, 11,108,352
    //   Qb  @ 149553152  : 34,078,720
    //   Kb  @ 183631872  : 34,078,720
    //   Vb  @ 217710592  : 34,078,720 (layer-0 V rows, pre-transpose)
    //   Hp  @ 251789312  : 256 x 1024 f32 = 1,048,576
    char* ws = (char*)d_ws;
    BF16* Xb = (BF16*)ws;
    BF16* X = Xb;
    BF16* Vt = (BF16*)(ws + 34078720L);
    BF16* Wc = (BF16*)(ws + 138444800L);
    BF16* Qb = (BF16*)(ws + 149553152L);
    BF16* Kb = (BF16*)(ws + 183631872L);
    BF16* Vb = (BF16*)(ws + 217710592L);
    float* Hp = (float*)(ws + 251789312L);

    BF16* w0 = Wc;                      // packed [1536][2080]: Wq0|Wk0|Wv0
    BF16* wl = Wc + 3L * 512 * 2080;    // 3 layers, each packed [1536][512]

    auto cvt = [&](const float* src, BF16* dst, long R, int Ks, int Kd) {
        long pairs = R * Kd / 2;
        int blocks = (int)((pairs + 255) / 256);
        convert_pad_k<<<blocks, 256, 0, stream>>>(src, dst, pairs, Ks, Kd);
    };
    cvt(dataL, Xb, 16640, 2053, 2080);
    cvt(dataR, Xb + 16640L * 2080, 16640, 2053, 2080);
    cvt(Wq0, w0, 512, 2053, 2080);
    cvt(Wk0, w0 + 512L * 2080, 512, 2053, 2080);
    cvt(Wv0, w0 + 2L * 512 * 2080, 512, 2053, 2080);
    for (int n = 0; n < 3; ++n) {
        BF16* base = wl + (long)n * 3 * 262144;
        cvt(Wq + (long)n * 262144, base, 512, 512, 512);
        cvt(Wk + (long)n * 262144, base + 262144, 512, 512, 512);
        cvt(Wv + (long)n * 262144, base + 2 * 262144, 512, 512, 512);
    }

    dim3 ggrid(12, 260);
    // layer 0: V to row layout (Xb still live), then transpose
    gemm_qkv<<<ggrid, 256, 0, stream>>>(Xb, w0, bq0, bk0, bv0, Qb, Kb, Vb, 2080, 0);
    vtrans_k<<<512, 256, 0, stream>>>((const ushort*)Vb, (ushort*)Vt);
    attn_fused<<<512, 256, 0, stream>>>(Qb, Kb, Vt, X, 0);
    // layers 1..3: V written transposed directly
    for (int n = 0; n < 3; ++n) {
        gemm_qkv<<<ggrid, 256, 0, stream>>>(X, wl + (long)n * 3 * 262144,
                                            bq + n * 512, bk + n * 512, bv + n * 512,
                                            Qb, Kb, Vt, 512, 1);
        attn_fused<<<512, 256, 0, stream>>>(Qb, Kb, Vt, X, 1);
    }
    pool_k<<<512, 256, 0, stream>>>(X, Hp);
    fc_k<<<256, 256, 0, stream>>>(Hp, W1, b1, W2, b2, (float*)d_out);
}

// Round 3
// 1429.544 us; speedup vs baseline: 1.1644x; 1.1194x over previous
//
#include <hip/hip_runtime.h>
#include <hip/hip_bf16.h>

#define BF16 __hip_bfloat16

typedef __bf16 bf16x8 __attribute__((ext_vector_type(8)));
typedef float f32x4 __attribute__((ext_vector_type(4)));

__device__ __forceinline__ void async_copy16(const void* g, void* l) {
    __builtin_amdgcn_global_load_lds(
        (const __attribute__((address_space(1))) void*)g,
        (__attribute__((address_space(3))) void*)l,
        16, 0, 0);
}

// ---------------- fp32 -> bf16 convert with K padding ----------------
__global__ __launch_bounds__(256) void convert_pad_k(
    const float* __restrict__ src, BF16* __restrict__ dst,
    long pairs, int Ks, int Kd) {
    long p = (long)blockIdx.x * blockDim.x + threadIdx.x;
    if (p >= pairs) return;
    long e = p * 2;
    long r = e / Kd;
    int k = (int)(e - r * Kd);
    float a = (k < Ks) ? src[r * Ks + k] : 0.f;
    float b = (k + 1 < Ks) ? src[r * Ks + k + 1] : 0.f;
    dst[e] = __float2bfloat16(a);
    dst[e + 1] = __float2bfloat16(b);
}

// ---------------- fused QKV NT GEMM, BK=64 as two 32-wide sub-tiles ----------------
// X: [N][K] bf16, W packed: [1536][K] = Wq|Wk|Wv. grid (12, 260): x = m-tile, y = n-tile.
// sel = x>>2 routes output: Q rows, K rows, V (vtmode: transposed [bb][c][96], else rows).
// K must be a multiple of 64.
__global__ __launch_bounds__(256, 3) void gemm_qkv(
    const BF16* __restrict__ Xg, const BF16* __restrict__ Wg,
    const float* __restrict__ bqp, const float* __restrict__ bkp, const float* __restrict__ bvp,
    BF16* __restrict__ Qo, BF16* __restrict__ Ko, BF16* __restrict__ Vo,
    int K, int vtmode) {
    __shared__ __align__(16) BF16 Xs[2][128 * 32];
    __shared__ __align__(16) BF16 Ws[2][128 * 32];
    const int tid = threadIdx.x;
    const int w = tid >> 6;
    const int lane = tid & 63;
    const int quad = lane >> 4;
    const int l15 = lane & 15;
    const long n0 = (long)blockIdx.y * 128;
    const int m0full = blockIdx.x * 128;
    const int sel = blockIdx.x >> 2;
    const int mbase = (blockIdx.x & 3) * 128;
    const int wn = (w & 1) * 64;
    const int wm = (w >> 1) * 64;
    const int srow = lane >> 2;
    const int skoff = (lane & 3) * 8;
    f32x4 acc[4][4] = {};
    for (int k0 = 0; k0 < K; k0 += 64) {
#pragma unroll
        for (int sub = 0; sub < 2; ++sub) {
#pragma unroll
            for (int c = 0; c < 2; ++c) {
                const int rbase = w * 32 + c * 16;
                const int kcol = k0 + sub * 32 + skoff;
                async_copy16(Xg + (n0 + rbase + srow) * K + kcol, &Xs[sub][rbase * 32]);
                async_copy16(Wg + (long)(m0full + rbase + srow) * K + kcol, &Ws[sub][rbase * 32]);
            }
        }
        __syncthreads();
#pragma unroll
        for (int sub = 0; sub < 2; ++sub) {
            bf16x8 af[4], bfr[4];
#pragma unroll
            for (int i = 0; i < 4; ++i)
                af[i] = *(const bf16x8*)&Xs[sub][(wn + i * 16 + l15) * 32 + quad * 8];
#pragma unroll
            for (int j = 0; j < 4; ++j)
                bfr[j] = *(const bf16x8*)&Ws[sub][(wm + j * 16 + l15) * 32 + quad * 8];
#pragma unroll
            for (int i = 0; i < 4; ++i)
#pragma unroll
                for (int j = 0; j < 4; ++j)
                    acc[i][j] = __builtin_amdgcn_mfma_f32_16x16x32_bf16(af[i], bfr[j], acc[i][j], 0, 0, 0);
        }
        __syncthreads();
    }
    const float* bp = (sel == 0) ? bqp : (sel == 1) ? bkp : bvp;
    BF16* out = (sel == 0) ? Qo : (sel == 1) ? Ko : Vo;
#pragma unroll
    for (int j = 0; j < 4; ++j) {
        const int m = mbase + wm + j * 16 + l15;
        const float bz = bp[m];
#pragma unroll
        for (int i = 0; i < 4; ++i) {
#pragma unroll
            for (int r = 0; r < 4; ++r) {
                const long n = n0 + wn + i * 16 + quad * 4 + r;
                float v = acc[i][j][r] + bz;
                if (sel == 2) {
                    v = (v >= 0.f) ? v : 0.01f * v;
                    if (vtmode) {
                        const int ni = (int)n;
                        const int bb = ni / 65;
                        const int l = ni - bb * 65;
                        out[((long)bb * 512 + m) * 96 + l] = __float2bfloat16(v);
                        continue;
                    }
                }
                out[n * 512 + m] = __float2bfloat16(v);
            }
        }
    }
}

// ---------------- V transpose (layer 0 only): Vb[n][512] -> Vt[bb][c][96] ----------------
__global__ __launch_bounds__(256) void vtrans_k(const ushort* __restrict__ Vb,
                                                ushort* __restrict__ Vt) {
    const int bb = blockIdx.x;
    for (int idx = threadIdx.x; idx < 512 * 33; idx += 256) {
        const int c = idx / 33;
        const int m = (idx - c * 33) * 2;
        ushort a = Vb[((long)bb * 65 + m) * 512 + c];
        ushort b = (m + 1 < 65) ? Vb[((long)bb * 65 + m + 1) * 512 + c] : (ushort)0;
        *(uint*)&Vt[((long)bb * 512 + c) * 96 + m] = (uint)a | ((uint)b << 16);
    }
}

// ---------------- scores + softmax: P[bb][65][96] normalized bf16 ----------------
// Q,K: [33280][512] bf16. One block per bb. 25 S-tiles balanced over 4 waves.
__global__ __launch_bounds__(256) void attn_scores(
    const BF16* __restrict__ Qg, const BF16* __restrict__ Kg, BF16* __restrict__ Pg) {
    constexpr float SC = 0.04419417382415922f;  // 1/sqrt(512)
    __shared__ __align__(16) BF16 Qs[2][80 * 32];
    __shared__ __align__(16) BF16 Ks[2][80 * 32];
    __shared__ float Sf[80 * 84];
    const int bb = blockIdx.x;
    const int tid = threadIdx.x;
    const int w = tid >> 6, lane = tid & 63, quad = lane >> 4, l15 = lane & 15;
    // per-wave tile list: t = w + 4*u over 25 tiles (wave0: 7, others: 6)
    int i16[7], j16[7], nt = 0;
    for (int t = w; t < 25; t += 4) {
        i16[nt] = (t / 5) * 16;
        j16[nt] = (t % 5) * 16;
        ++nt;
    }
    f32x4 acc[7] = {};
    for (int k0 = 0; k0 < 512; k0 += 64) {
        for (int idx = tid; idx < 1280; idx += 256) {
            const int t = (idx >= 640) ? 1 : 0;
            const int e = idx - t * 640;
            const int sub = (e >= 320) ? 1 : 0;
            const int e2 = e - sub * 320;
            const int row = e2 >> 2;
            const int koff = (e2 & 3) * 8;
            uint4 val = make_uint4(0, 0, 0, 0);
            if (row < 65) {
                const BF16* src = (t ? Kg : Qg) + ((long)(bb * 65 + row) * 512 + k0 + sub * 32 + koff);
                val = *(const uint4*)src;
            }
            *(uint4*)&((t ? Ks : Qs)[sub][row * 32 + koff]) = val;
        }
        __syncthreads();
#pragma unroll
        for (int sub = 0; sub < 2; ++sub) {
            for (int u = 0; u < nt; ++u) {
                bf16x8 af = *(const bf16x8*)&Qs[sub][(i16[u] + l15) * 32 + quad * 8];
                bf16x8 bfr = *(const bf16x8*)&Ks[sub][(j16[u] + l15) * 32 + quad * 8];
                acc[u] = __builtin_amdgcn_mfma_f32_16x16x32_bf16(af, bfr, acc[u], 0, 0, 0);
            }
        }
        __syncthreads();
    }
    for (int u = 0; u < nt; ++u)
#pragma unroll
        for (int r = 0; r < 4; ++r)
            Sf[(i16[u] + quad * 4 + r) * 84 + j16[u] + l15] = acc[u][r] * SC;
    __syncthreads();
    // softmax: 4 threads per row
    for (int rr = tid >> 2; rr < 65; rr += 64) {
        const int sub = tid & 3;
        float mx = -1e30f;
        for (int m = sub; m < 65; m += 4) mx = fmaxf(mx, Sf[rr * 84 + m]);
        mx = fmaxf(mx, __shfl_xor(mx, 1));
        mx = fmaxf(mx, __shfl_xor(mx, 2));
        float s = 0.f;
        for (int m = sub; m < 65; m += 4) {
            float e = __expf(Sf[rr * 84 + m] - mx);
            Sf[rr * 84 + m] = e;
            s += e;
        }
        s += __shfl_xor(s, 1);
        s += __shfl_xor(s, 2);
        const float inv = 1.f / s;
        const long base = ((long)bb * 65 + rr) * 96;
        for (int m = sub; m < 96; m += 4) {
            float v = (m < 65) ? Sf[rr * 84 + m] * inv : 0.f;
            Pg[base + m] = __float2bfloat16(v);
        }
    }
}

// ---------------- PV + residual: grid (512, 4) = (bb, 128-c strip) ----------------
// P: [bb][65][96] normalized bf16; Vt: [bb][c][96]; X: [33280][512] in/out.
__global__ __launch_bounds__(256) void attn_pv(
    const BF16* __restrict__ Pg, const BF16* __restrict__ Vt,
    BF16* __restrict__ Xg, int residual) {
    __shared__ __align__(16) BF16 Ps[80 * 104];
    const int bb = blockIdx.x;
    const int c0 = blockIdx.y * 128;
    const int tid = threadIdx.x;
    const int w = tid >> 6, lane = tid & 63, quad = lane >> 4, l15 = lane & 15;
    for (int idx = tid; idx < 960; idx += 256) {
        const int row = idx / 12;
        const int kk = idx - row * 12;
        uint4 val = make_uint4(0, 0, 0, 0);
        if (row < 65) val = *(const uint4*)(Pg + ((long)bb * 65 + row) * 96 + kk * 8);
        *(uint4*)&Ps[row * 104 + kk * 8] = val;
    }
    __syncthreads();
    bf16x8 af[5][3];
#pragma unroll
    for (int i = 0; i < 5; ++i)
#pragma unroll
        for (int ks = 0; ks < 3; ++ks)
            af[i][ks] = *(const bf16x8*)&Ps[(i * 16 + l15) * 104 + ks * 32 + quad * 8];
#pragma unroll
    for (int jj = 0; jj < 2; ++jj) {
        const int c = c0 + (jj * 4 + w) * 16 + l15;
        const BF16* vp = Vt + ((long)bb * 512 + c) * 96 + quad * 8;
        bf16x8 b0 = *(const bf16x8*)vp;
        bf16x8 b1 = *(const bf16x8*)(vp + 32);
        bf16x8 b2 = *(const bf16x8*)(vp + 64);
        f32x4 po[5] = {};
#pragma unroll
        for (int i = 0; i < 5; ++i) {
            po[i] = __builtin_amdgcn_mfma_f32_16x16x32_bf16(af[i][0], b0, po[i], 0, 0, 0);
            po[i] = __builtin_amdgcn_mfma_f32_16x16x32_bf16(af[i][1], b1, po[i], 0, 0, 0);
            po[i] = __builtin_amdgcn_mfma_f32_16x16x32_bf16(af[i][2], b2, po[i], 0, 0, 0);
        }
#pragma unroll
        for (int i = 0; i < 5; ++i)
#pragma unroll
            for (int r = 0; r < 4; ++r) {
                const int l = i * 16 + quad * 4 + r;
                if (l < 65) {
                    const long idx = ((long)(bb * 65 + l)) * 512 + c;
                    float v = po[i][r];
                    if (residual) v += __bfloat162float(Xg[idx]);
                    Xg[idx] = __float2bfloat16(v);
                }
            }
    }
}

// ---------------- mean over L -> Hp[b][s*512+c] fp32 ----------------
__global__ __launch_bounds__(256) void pool_k(const BF16* __restrict__ Xg,
                                              float* __restrict__ Hp) {
    const int sb = blockIdx.x;
    const int s = sb >> 8, b = sb & 255;
    for (int c = threadIdx.x; c < 512; c += 256) {
        float acc = 0.f;
        for (int l = 0; l < 65; ++l)
            acc += __bfloat162float(Xg[((long)sb * 65 + l) * 512 + c]);
        Hp[(long)b * 1024 + s * 512 + c] = acc * (1.f / 65.f);
    }
}

// ---------------- classifier ----------------
__global__ __launch_bounds__(256) void fc_k(
    const float* __restrict__ Hp, const float* __restrict__ W1,
    const float* __restrict__ b1, const float* __restrict__ W2,
    const float* __restrict__ b2, float* __restrict__ out) {
    __shared__ float h[1024];
    __shared__ float h1[256];
    const int b = blockIdx.x, tid = threadIdx.x;
    for (int k = tid; k < 1024; k += 256) h[k] = Hp[(long)b * 1024 + k];
    __syncthreads();
    float acc = b1[tid];
    for (int k = 0; k < 1024; ++k) acc += W1[(long)tid * 1024 + k] * h[k];
    h1[tid] = fmaxf(acc, 0.f);
    __syncthreads();
    const int w = tid >> 6, lane = tid & 63;
    if (w < 2) {
        float p = 0.f;
        for (int u = lane; u < 256; u += 64) p += W2[w * 256 + u] * h1[u];
        for (int off = 32; off > 0; off >>= 1) p += __shfl_down(p, off);
        if (lane == 0) out[b * 2 + w] = p + b2[w];
    }
}

extern "C" void kernel_launch(void* const* d_in, const int* in_sizes, int n_in,
                              void* d_out, int out_size, void* d_ws, size_t ws_size,
                              hipStream_t stream) {
    const float* dataL = (const float*)d_in[0];
    const float* dataR = (const float*)d_in[1];
    const float* Wq0 = (const float*)d_in[2];
    const float* bq0 = (const float*)d_in[3];
    const float* Wk0 = (const float*)d_in[4];
    const float* bk0 = (const float*)d_in[5];
    const float* Wv0 = (const float*)d_in[6];
    const float* bv0 = (const float*)d_in[7];
    const float* Wq = (const float*)d_in[8];
    const float* bq = (const float*)d_in[9];
    const float* Wk = (const float*)d_in[10];
    const float* bk = (const float*)d_in[11];
    const float* Wv = (const float*)d_in[12];
    const float* bv = (const float*)d_in[13];
    const float* W1 = (const float*)d_in[14];
    const float* b1 = (const float*)d_in[15];
    const float* W2 = (const float*)d_in[16];
    const float* b2 = (const float*)d_in[17];

    // ws layout (bytes), total 254,017,536:
    //   Xb @ 0          : 33280 x 2112 bf16 = 140,574,720 (dead after L0 GEMM; region reused:)
    //     X  @ 0        : 34,078,720
    //     Vt @ 34078720 : 512*512*96*2 = 50,331,648  (ends 84,410,368)
    //     Pg @ 84410368 : 512*65*96*2  = 6,389,760   (ends 90,800,128)
    //     Hp @ 90800128 : 256*1024*4   = 1,048,576   (ends 91,848,704)
    //   Wc @ 140574720  : w0 1536x2112 bf16 = 6,488,064 ; wl 9x512x512 bf16 = 4,718,592
    //   Qb @ 151781376  : 34,078,720
    //   Kb @ 185860096  : 34,078,720
    //   Vb @ 219938816  : 34,078,720
    char* ws = (char*)d_ws;
    BF16* Xb = (BF16*)ws;
    BF16* X = Xb;
    BF16* Vt = (BF16*)(ws + 34078720L);
    BF16* Pg = (BF16*)(ws + 84410368L);
    float* Hp = (float*)(ws + 90800128L);
    BF16* Wc = (BF16*)(ws + 140574720L);
    BF16* Qb = (BF16*)(ws + 151781376L);
    BF16* Kb = (BF16*)(ws + 185860096L);
    BF16* Vb = (BF16*)(ws + 219938816L);

    BF16* w0 = Wc;                      // packed [1536][2112]: Wq0|Wk0|Wv0
    BF16* wl = Wc + 3L * 512 * 2112;    // 3 layers, each packed [1536][512]

    auto cvt = [&](const float* src, BF16* dst, long R, int Ks, int Kd) {
        long pairs = R * Kd / 2;
        int blocks = (int)((pairs + 255) / 256);
        convert_pad_k<<<blocks, 256, 0, stream>>>(src, dst, pairs, Ks, Kd);
    };
    cvt(dataL, Xb, 16640, 2053, 2112);
    cvt(dataR, Xb + 16640L * 2112, 16640, 2053, 2112);
    cvt(Wq0, w0, 512, 2053, 2112);
    cvt(Wk0, w0 + 512L * 2112, 512, 2053, 2112);
    cvt(Wv0, w0 + 2L * 512 * 2112, 512, 2053, 2112);
    for (int n = 0; n < 3; ++n) {
        BF16* base = wl + (long)n * 3 * 262144;
        cvt(Wq + (long)n * 262144, base, 512, 512, 512);
        cvt(Wk + (long)n * 262144, base + 262144, 512, 512, 512);
        cvt(Wv + (long)n * 262144, base + 2 * 262144, 512, 512, 512);
    }

    dim3 ggrid(12, 260);
    dim3 pvgrid(512, 4);
    // layer 0: V to row layout (Xb still live), then transpose
    gemm_qkv<<<ggrid, 256, 0, stream>>>(Xb, w0, bq0, bk0, bv0, Qb, Kb, Vb, 2112, 0);
    vtrans_k<<<512, 256, 0, stream>>>((const ushort*)Vb, (ushort*)Vt);
    attn_scores<<<512, 256, 0, stream>>>(Qb, Kb, Pg);
    attn_pv<<<pvgrid, 256, 0, stream>>>(Pg, Vt, X, 0);
    // layers 1..3: V written transposed directly by the GEMM epilogue
    for (int n = 0; n < 3; ++n) {
        gemm_qkv<<<ggrid, 256, 0, stream>>>(X, wl + (long)n * 3 * 262144,
                                            bq + n * 512, bk + n * 512, bv + n * 512,
                                            Qb, Kb, Vt, 512, 1);
        attn_scores<<<512, 256, 0, stream>>>(Qb, Kb, Pg);
        attn_pv<<<pvgrid, 256, 0, stream>>>(Pg, Vt, X, 1);
    }
    pool_k<<<512, 256, 0, stream>>>(X, Hp);
    fc_k<<<256, 256, 0, stream>>>(Hp, W1, b1, W2, b2, (float*)d_out);
}